// Round 2
// baseline (791.439 us; speedup 1.0000x reference)
//
#include <hip/hip_runtime.h>

// ---------------- constants ----------------
#define S      4096
#define DM     1024
#define NB     4
#define NH     16
#define HDIM   64
#define MTOT   (NB * S)          // 16384
#define DS     ((long)DM * S)    // 4,194,304

typedef __attribute__((ext_vector_type(8))) short short8;
typedef __attribute__((ext_vector_type(4))) float f32x4;
typedef __attribute__((ext_vector_type(8))) unsigned short u16x8;
typedef __attribute__((ext_vector_type(4))) unsigned short u16x4;

__device__ __forceinline__ unsigned short f2bf(float f) {
  union { float f; unsigned u; } v; v.f = f;
  unsigned r = v.u + 0x7fffu + ((v.u >> 16) & 1u);   // RNE
  return (unsigned short)(r >> 16);
}
__device__ __forceinline__ float bf2f(short h) {
  union { unsigned u; float f; } v; v.u = ((unsigned)(unsigned short)h) << 16;
  return v.f;
}

#define GLOAD(gp, lp) __builtin_amdgcn_global_load_lds( \
    (const __attribute__((address_space(1))) void*)(gp), \
    (__attribute__((address_space(3))) void*)(lp), 16, 0, 0)

// ---------------- small kernels ----------------

// cos table + spectral filter coefficients c[k] = cos(alpha' * atan(log(|f_k|+1e-10)))
// note c_arr[0] == c0 == sum_j g[j]  (the bias pass-through factor)
__global__ void k_tables(const float* __restrict__ fd, const float* __restrict__ alpha,
                         const float* __restrict__ fsc,
                         float* __restrict__ cos_tab, float* __restrict__ c_arr) {
  int k = blockIdx.x * 256 + threadIdx.x;
  if (k >= S) return;
  float aa = alpha[0] + fsc[0] * (fd[0] - 1.5f);
  const float twopi = 6.28318530717958647692f;
  cos_tab[k] = cosf(twopi * ((float)k / (float)S));
  int kk = (k <= S / 2) ? k : (S - k);
  float af = (float)kk / (float)S;
  c_arr[k] = cosf(aa * atanf(logf(af + 1e-10f)));
}

// g[j] = (1/S) sum_k c[k] * cos(2*pi*j*k/S)
__global__ void k_g(const float* __restrict__ cos_tab, const float* __restrict__ c_arr,
                    float* __restrict__ g) {
  __shared__ float sct[S];
  __shared__ float sc[S];
  for (int i = threadIdx.x; i < S; i += 256) { sct[i] = cos_tab[i]; sc[i] = c_arr[i]; }
  __syncthreads();
  int j = blockIdx.x * 256 + threadIdx.x;
  float acc = 0.f;
  int t = 0;
  for (int k = 0; k < S; ++k) {
    acc += sc[k] * sct[t];
    t = (t + j) & (S - 1);
  }
  g[j] = acc * (1.f / (float)S);
}

// G[n][m] = bf16(g[(n-m) mod S])
__global__ void k_buildG(const float* __restrict__ g, short* __restrict__ G) {
  long i8 = ((long)blockIdx.x * 256 + threadIdx.x) * 8;
  if (i8 >= (long)S * S) return;
  int n = (int)(i8 >> 12);
  int m = (int)(i8 & (S - 1));
  u16x8 gv;
#pragma unroll
  for (int j = 0; j < 8; ++j) gv[j] = f2bf(g[(n - m - j) & (S - 1)]);
  *(u16x8*)(G + i8) = gv;
}

// Mc[n][m] = bf16(cos(2*pi*n*m/S)/64)
__global__ void k_buildM(const float* __restrict__ cos_tab, short* __restrict__ Mc) {
  long i8 = ((long)blockIdx.x * 256 + threadIdx.x) * 8;
  if (i8 >= (long)S * S) return;
  int n = (int)(i8 >> 12);
  int m = (int)(i8 & (S - 1));
  u16x8 mv;
#pragma unroll
  for (int j = 0; j < 8; ++j) mv[j] = f2bf(cos_tab[(n * (m + j)) & (S - 1)] * 0.015625f);
  *(u16x8*)(Mc + i8) = mv;
}

// W [K][N] fp32 -> WT [N][K] bf16 (transpose-cast)
__global__ void k_castWT(const float* __restrict__ W, short* __restrict__ WT) {
  int idx = blockIdx.x * 256 + threadIdx.x;
  if (idx >= DM * DM) return;
  int nrow = idx >> 10, kcol = idx & (DM - 1);
  WT[idx] = (short)f2bf(W[kcol * DM + nrow]);
}

// x [b][s][d] fp32 -> xt [b][d][s] bf16 (tiled transpose-cast)
__global__ void k_transX(const float* __restrict__ x, short* __restrict__ xt) {
  __shared__ float tile[64][65];
  int s0 = blockIdx.x * 64, d0 = blockIdx.y * 64, b = blockIdx.z;
  int t = threadIdx.x;
  int r = t >> 4, c4 = (t & 15) * 4;
  const float* xp = x + ((long)(b * S + s0) * DM) + d0;
#pragma unroll
  for (int rr = 0; rr < 4; ++rr) {
    float4 v = *(const float4*)(xp + (long)(r + rr * 16) * DM + c4);
    tile[r + rr * 16][c4 + 0] = v.x;
    tile[r + rr * 16][c4 + 1] = v.y;
    tile[r + rr * 16][c4 + 2] = v.z;
    tile[r + rr * 16][c4 + 3] = v.w;
  }
  __syncthreads();
  int s_loc = t & 63, dq = t >> 6;
  short* op = xt + ((long)(b * DM + d0) * S) + s0;
#pragma unroll
  for (int i = 0; i < 16; ++i) {
    int d_loc = dq * 16 + i;
    op[(long)d_loc * S + s_loc] = (short)f2bf(tile[s_loc][d_loc]);
  }
}

// logits[b][h][s] = (1/8) * sum_j qt[b][h*64+j][s] * kt[b][h*64+j][s]
__global__ void k_logits(const short* __restrict__ Qt, const short* __restrict__ Kt,
                         float* __restrict__ logits) {
  int s = blockIdx.x * 256 + threadIdx.x;
  int h = blockIdx.y, b = blockIdx.z;
  const short* q = Qt + ((long)b * DM + h * HDIM) * S + s;
  const short* k = Kt + ((long)b * DM + h * HDIM) * S + s;
  float acc = 0.f;
#pragma unroll 8
  for (int j = 0; j < HDIM; ++j)
    acc += bf2f(q[(long)j * S]) * bf2f(k[(long)j * S]);
  logits[((long)b * NH + h) * S + s] = acc * 0.125f;
}

// softmax over heads: w[b][h][s]
__global__ void k_softw(const float* __restrict__ logits, float* __restrict__ w) {
  int idx = blockIdx.x * 256 + threadIdx.x;   // b*S + s
  if (idx >= NB * S) return;
  int b = idx >> 12, s = idx & (S - 1);
  const float* lp = logits + (long)b * NH * S + s;
  float v[NH];
  float m = -1e30f;
#pragma unroll
  for (int h = 0; h < NH; ++h) { v[h] = lp[(long)h * S]; m = fmaxf(m, v[h]); }
  float sum = 0.f;
#pragma unroll
  for (int h = 0; h < NH; ++h) { v[h] = expf(v[h] - m); sum += v[h]; }
  float inv = 1.f / sum;
  float* wp = w + (long)b * NH * S + s;
#pragma unroll
  for (int h = 0; h < NH; ++h) wp[(long)h * S] = v[h] * inv;
}

// in-place: vt[b][d][s] *= w[b][d>>6][s]   (bf16)
__global__ void k_att(short* vt, const float* __restrict__ wsm) {
  long i8 = ((long)blockIdx.x * 256 + threadIdx.x) * 8;
  if (i8 >= (long)NB * DS) return;
  int b = (int)(i8 >> 22);
  long r = i8 & (DS - 1);
  int d = (int)(r >> 12);
  int s = (int)(r & (S - 1));
  int h = d >> 6;
  const float* wp = wsm + ((long)b * NH + h) * S + s;
  u16x8 vv = *(const u16x8*)(vt + i8);
  u16x8 ov;
#pragma unroll
  for (int j = 0; j < 8; ++j) ov[j] = f2bf(wp[j] * bf2f((short)vv[j]));
  *(u16x8*)(vt + i8) = ov;
}

// ---------------- GEMM ----------------
// C = A @ B ; A row-major [M,K] bf16, B given TRANSPOSED as Bt [N,K] bf16.
// EPI 0: write bf16 C[M,N] normal (per-batch via cBatch)
// EPI 1: write bf16 transposed into [b][col][s] layout (b=row>>12, s=row&4095), bias[col]*bsc
// EPI 2: write fp32 C[M,N] + bias[col] + resid[row,col]
template <int EPI>
__global__ __launch_bounds__(256) void gemm_kernel(
    const short* __restrict__ A, const short* __restrict__ Bt,
    short* __restrict__ Cb, float* __restrict__ Cf,
    const float* __restrict__ bias, const float* __restrict__ bsc,
    const float* __restrict__ resid,
    int M, int N, int K, long aBatch, long bBatch, long cBatch) {
  __shared__ __align__(16) short As[2][128 * 32];
  __shared__ __align__(16) short Bs[2][128 * 32];
  const int bz = blockIdx.z;
  const short* Ag = A + (long)bz * aBatch;
  const short* Bg = Bt + (long)bz * bBatch;
  const int m0 = blockIdx.x * 128, n0 = blockIdx.y * 128;
  const int tid = threadIdx.x;
  const int lane = tid & 63, wave = tid >> 6;
  const int wm = wave >> 1, wn = wave & 1;
  const int srow = tid >> 2;            // 0..63
  const int ssub = (tid & 3) * 8;       // shorts within 32-elem row

  f32x4 zero = {0.f, 0.f, 0.f, 0.f};
  f32x4 acc[4][4];
#pragma unroll
  for (int i = 0; i < 4; ++i)
#pragma unroll
    for (int j = 0; j < 4; ++j) acc[i][j] = zero;

  auto stage = [&](int buf, int kt) {
    const long ka = (long)kt * 32 + ssub;
    const short* a0 = Ag + (long)(m0 + srow) * K + ka;
    const short* a1 = Ag + (long)(m0 + 64 + srow) * K + ka;
    const short* b0 = Bg + (long)(n0 + srow) * K + ka;
    const short* b1 = Bg + (long)(n0 + 64 + srow) * K + ka;
    short* la = &As[buf][srow * 32 + ssub];
    short* lb = &Bs[buf][srow * 32 + ssub];
    GLOAD(a0, la);
    GLOAD(a1, la + 64 * 32);
    GLOAD(b0, lb);
    GLOAD(b1, lb + 64 * 32);
  };

  const int nt = K >> 5;
  stage(0, 0);
  asm volatile("s_waitcnt vmcnt(0)" ::: "memory");
  __syncthreads();
  int cur = 0;
  for (int t = 0; t < nt; ++t) {
    if (t + 1 < nt) stage(cur ^ 1, t + 1);
    const short* as = &As[cur][(wm * 64 + (lane & 15)) * 32 + (lane >> 4) * 8];
    const short* bs = &Bs[cur][(wn * 64 + (lane & 15)) * 32 + (lane >> 4) * 8];
    short8 af[4], bb[4];
#pragma unroll
    for (int i = 0; i < 4; ++i) af[i] = *(const short8*)(as + i * 16 * 32);
#pragma unroll
    for (int i = 0; i < 4; ++i) bb[i] = *(const short8*)(bs + i * 16 * 32);
#pragma unroll
    for (int i = 0; i < 4; ++i)
#pragma unroll
      for (int j = 0; j < 4; ++j)
        acc[i][j] = __builtin_amdgcn_mfma_f32_16x16x32_bf16(af[i], bb[j], acc[i][j], 0, 0, 0);
    asm volatile("s_waitcnt vmcnt(0)" ::: "memory");
    __syncthreads();
    cur ^= 1;
  }

  // epilogue: C/D layout col = lane&15, row = (lane>>4)*4 + reg
#pragma unroll
  for (int mf = 0; mf < 4; ++mf) {
    const int rbase = m0 + wm * 64 + mf * 16 + ((lane >> 4) << 2);
#pragma unroll
    for (int nf = 0; nf < 4; ++nf) {
      const int col = n0 + wn * 64 + nf * 16 + (lane & 15);
      f32x4 a = acc[mf][nf];
      if constexpr (EPI == 0) {
        short* cp = Cb + (long)bz * cBatch;
#pragma unroll
        for (int r = 0; r < 4; ++r)
          cp[(long)(rbase + r) * N + col] = (short)f2bf(a[r]);
      } else if constexpr (EPI == 1) {
        float sc = bsc ? bsc[0] : 1.f;
        float bi = bias ? bias[col] * sc : 0.f;
        int b_ = rbase >> 12;
        int s_ = rbase & (S - 1);
        long addr = ((long)(b_ * DM + col)) * S + s_;
        u16x4 pk;
#pragma unroll
        for (int r = 0; r < 4; ++r) pk[r] = f2bf(a[r] + bi);
        *(u16x4*)(Cb + addr) = pk;
      } else {
        float bi = bias[col];
#pragma unroll
        for (int r = 0; r < 4; ++r) {
          long o = (long)(rbase + r) * N + col;
          Cf[o] = a[r] + bi + resid[o];
        }
      }
    }
  }
}

// ---------------- launch ----------------
extern "C" void kernel_launch(void* const* d_in, const int* in_sizes, int n_in,
                              void* d_out, int out_size, void* d_ws, size_t ws_size,
                              hipStream_t stream) {
  const float* x     = (const float*)d_in[0];
  const float* fd    = (const float*)d_in[1];
  const float* Wq    = (const float*)d_in[2];
  const float* bq    = (const float*)d_in[3];
  const float* Wk    = (const float*)d_in[4];
  const float* bk    = (const float*)d_in[5];
  const float* Wv    = (const float*)d_in[6];
  const float* bv    = (const float*)d_in[7];
  const float* Wo    = (const float*)d_in[8];
  const float* bo    = (const float*)d_in[9];
  const float* alpha = (const float*)d_in[10];
  const float* fsc   = (const float*)d_in[11];
  float* out = (float*)d_out;

  // --- workspace layout (~106.5 MB total) ---
  char* wp = (char*)d_ws;
  auto alloc = [&](size_t bytes) {
    char* p = wp;
    wp += (bytes + 255) & ~(size_t)255;
    return p;
  };
  float* cos_tab = (float*)alloc(S * 4);
  float* c_arr   = (float*)alloc(S * 4);          // c_arr[0] = c0 bias factor
  float* g       = (float*)alloc(S * 4);
  float* logits  = (float*)alloc((size_t)NB * NH * S * 4);   // 1 MB
  float* wsm     = (float*)alloc((size_t)NB * NH * S * 4);   // 1 MB
  short* WqT = (short*)alloc((size_t)DM * DM * 2);           // 2 MB each
  short* WkT = (short*)alloc((size_t)DM * DM * 2);
  short* WvT = (short*)alloc((size_t)DM * DM * 2);
  short* WoT = (short*)alloc((size_t)DM * DM * 2);
  short* slotA = (short*)alloc((size_t)NB * DS * 2);  // 32 MB: XbT -> Vt/att
  short* slotB = (short*)alloc((size_t)NB * DS * 2);  // 32 MB: G   -> Mc
  short* slotC = (short*)alloc((size_t)NB * DS * 2);  // 32 MB: Xs  -> att_time

  // d_out as scratch until the final GEMM (written fully before each read)
  short* QtT = (short*)d_out;                 // 32 MB  [b][d][s] for b-pairs 0..
  short* KtT = (short*)d_out + (size_t)2 * DS;  // second 32 MB

  short* XbT = slotA;   // x transposed bf16 [b][d][s]
  short* Gm  = slotB;   // circulant spectral matrix
  short* Xs  = slotC;   // spectral(x) [b][s][d]
  short* VtT = slotA;   // v_t (after XbT dead)
  short* Mc  = slotB;   // cos ifft matrix (after Gm dead)
  short* att_time = slotC;  // (after Xs dead)

  dim3 blk(256);

  // tables + transform matrix
  k_tables<<<dim3(S / 256), blk, 0, stream>>>(fd, alpha, fsc, cos_tab, c_arr);
  k_g<<<dim3(S / 256), blk, 0, stream>>>(cos_tab, c_arr, g);
  k_buildG<<<dim3((unsigned)((long)S * S / 8 / 256)), blk, 0, stream>>>(g, Gm);

  // casts / transpose
  k_castWT<<<dim3(DM * DM / 256), blk, 0, stream>>>(Wq, WqT);
  k_castWT<<<dim3(DM * DM / 256), blk, 0, stream>>>(Wk, WkT);
  k_castWT<<<dim3(DM * DM / 256), blk, 0, stream>>>(Wv, WvT);
  k_castWT<<<dim3(DM * DM / 256), blk, 0, stream>>>(Wo, WoT);
  k_transX<<<dim3(S / 64, DM / 64, NB), blk, 0, stream>>>(x, XbT);

  // Xs_b = G @ X_b   (spectral applied ONCE, before projections)  [b][s][d] bf16
  dim3 gspec(S / 128, DM / 128, NB);
  gemm_kernel<0><<<gspec, blk, 0, stream>>>(Gm, XbT, Xs, nullptr, nullptr, nullptr, nullptr,
                                            S, DM, S, 0, DS, DS);

  // q_t/k_t/v_t = Xs @ W + c0*b, written transposed [b][d][s]
  dim3 gproj(MTOT / 128, DM / 128, 1);
  gemm_kernel<1><<<gproj, blk, 0, stream>>>(Xs, WqT, QtT, nullptr, bq, c_arr, nullptr,
                                            MTOT, DM, DM, 0, 0, 0);
  gemm_kernel<1><<<gproj, blk, 0, stream>>>(Xs, WkT, KtT, nullptr, bk, c_arr, nullptr,
                                            MTOT, DM, DM, 0, 0, 0);
  gemm_kernel<1><<<gproj, blk, 0, stream>>>(Xs, WvT, VtT, nullptr, bv, c_arr, nullptr,
                                            MTOT, DM, DM, 0, 0, 0);

  // logits, softmax over heads, attended (in-place on v_t)
  k_logits<<<dim3(S / 256, NH, NB), blk, 0, stream>>>(QtT, KtT, logits);
  k_softw<<<dim3(NB * S / 256), blk, 0, stream>>>(logits, wsm);
  k_att<<<dim3((unsigned)((long)NB * DS / 8 / 256)), blk, 0, stream>>>(VtT, wsm);

  // Mc (re-using Gm slot), then attended_time_b = Mc @ att_b -> [b][s][d]
  k_buildM<<<dim3((unsigned)((long)S * S / 8 / 256)), blk, 0, stream>>>(cos_tab, Mc);
  gemm_kernel<0><<<gspec, blk, 0, stream>>>(Mc, VtT, att_time, nullptr, nullptr, nullptr, nullptr,
                                            S, DM, S, 0, DS, DS);

  // out = att_time @ Wo + bo + x   (fp32; d_out scratch fully dead by now)
  gemm_kernel<2><<<gproj, blk, 0, stream>>>(att_time, WoT, nullptr, out, bo, nullptr, x,
                                            MTOT, DM, DM, 0, 0, 0);
}

// Round 3
// 636.356 us; speedup vs baseline: 1.2437x; 1.2437x over previous
//
#include <hip/hip_runtime.h>

// ---------------- constants ----------------
#define S      4096
#define DM     1024
#define NB     4
#define NH     16
#define HDIM   64
#define MTOT   (NB * S)          // 16384
#define DS     ((long)DM * S)    // 4,194,304

typedef __attribute__((ext_vector_type(8))) short short8;
typedef __attribute__((ext_vector_type(4))) float f32x4;
typedef __attribute__((ext_vector_type(8))) unsigned short u16x8;
typedef __attribute__((ext_vector_type(4))) unsigned short u16x4;

__device__ __forceinline__ unsigned short f2bf(float f) {
  union { float f; unsigned u; } v; v.f = f;
  unsigned r = v.u + 0x7fffu + ((v.u >> 16) & 1u);   // RNE
  return (unsigned short)(r >> 16);
}
__device__ __forceinline__ float bf2f(short h) {
  union { unsigned u; float f; } v; v.u = ((unsigned)(unsigned short)h) << 16;
  return v.f;
}

#define GLOAD(gp, lp) __builtin_amdgcn_global_load_lds( \
    (const __attribute__((address_space(1))) void*)(gp), \
    (__attribute__((address_space(3))) void*)(lp), 16, 0, 0)

#define SBAR() do { asm volatile("" ::: "memory"); __builtin_amdgcn_s_barrier(); \
                    asm volatile("" ::: "memory"); } while (0)
#define WAITL0() asm volatile("s_waitcnt lgkmcnt(0)" ::: "memory")

// ---------------- small kernels (unchanged, verified in R2) ----------------

__global__ void k_tables(const float* __restrict__ fd, const float* __restrict__ alpha,
                         const float* __restrict__ fsc,
                         float* __restrict__ cos_tab, float* __restrict__ c_arr) {
  int k = blockIdx.x * 256 + threadIdx.x;
  if (k >= S) return;
  float aa = alpha[0] + fsc[0] * (fd[0] - 1.5f);
  const float twopi = 6.28318530717958647692f;
  cos_tab[k] = cosf(twopi * ((float)k / (float)S));
  int kk = (k <= S / 2) ? k : (S - k);
  float af = (float)kk / (float)S;
  c_arr[k] = cosf(aa * atanf(logf(af + 1e-10f)));
}

__global__ void k_g(const float* __restrict__ cos_tab, const float* __restrict__ c_arr,
                    float* __restrict__ g) {
  __shared__ float sct[S];
  __shared__ float sc[S];
  for (int i = threadIdx.x; i < S; i += 256) { sct[i] = cos_tab[i]; sc[i] = c_arr[i]; }
  __syncthreads();
  int j = blockIdx.x * 256 + threadIdx.x;
  float acc = 0.f;
  int t = 0;
  for (int k = 0; k < S; ++k) {
    acc += sc[k] * sct[t];
    t = (t + j) & (S - 1);
  }
  g[j] = acc * (1.f / (float)S);
}

__global__ void k_buildG(const float* __restrict__ g, short* __restrict__ G) {
  long i8 = ((long)blockIdx.x * 256 + threadIdx.x) * 8;
  if (i8 >= (long)S * S) return;
  int n = (int)(i8 >> 12);
  int m = (int)(i8 & (S - 1));
  u16x8 gv;
#pragma unroll
  for (int j = 0; j < 8; ++j) gv[j] = f2bf(g[(n - m - j) & (S - 1)]);
  *(u16x8*)(G + i8) = gv;
}

__global__ void k_buildM(const float* __restrict__ cos_tab, short* __restrict__ Mc) {
  long i8 = ((long)blockIdx.x * 256 + threadIdx.x) * 8;
  if (i8 >= (long)S * S) return;
  int n = (int)(i8 >> 12);
  int m = (int)(i8 & (S - 1));
  u16x8 mv;
#pragma unroll
  for (int j = 0; j < 8; ++j) mv[j] = f2bf(cos_tab[(n * (m + j)) & (S - 1)] * 0.015625f);
  *(u16x8*)(Mc + i8) = mv;
}

__global__ void k_castWT(const float* __restrict__ W, short* __restrict__ WT) {
  int idx = blockIdx.x * 256 + threadIdx.x;
  if (idx >= DM * DM) return;
  int nrow = idx >> 10, kcol = idx & (DM - 1);
  WT[idx] = (short)f2bf(W[kcol * DM + nrow]);
}

__global__ void k_transX(const float* __restrict__ x, short* __restrict__ xt) {
  __shared__ float tile[64][65];
  int s0 = blockIdx.x * 64, d0 = blockIdx.y * 64, b = blockIdx.z;
  int t = threadIdx.x;
  int r = t >> 4, c4 = (t & 15) * 4;
  const float* xp = x + ((long)(b * S + s0) * DM) + d0;
#pragma unroll
  for (int rr = 0; rr < 4; ++rr) {
    float4 v = *(const float4*)(xp + (long)(r + rr * 16) * DM + c4);
    tile[r + rr * 16][c4 + 0] = v.x;
    tile[r + rr * 16][c4 + 1] = v.y;
    tile[r + rr * 16][c4 + 2] = v.z;
    tile[r + rr * 16][c4 + 3] = v.w;
  }
  __syncthreads();
  int s_loc = t & 63, dq = t >> 6;
  short* op = xt + ((long)(b * DM + d0) * S) + s0;
#pragma unroll
  for (int i = 0; i < 16; ++i) {
    int d_loc = dq * 16 + i;
    op[(long)d_loc * S + s_loc] = (short)f2bf(tile[s_loc][d_loc]);
  }
}

__global__ void k_logits(const short* __restrict__ Qt, const short* __restrict__ Kt,
                         float* __restrict__ logits) {
  int s = blockIdx.x * 256 + threadIdx.x;
  int h = blockIdx.y, b = blockIdx.z;
  const short* q = Qt + ((long)b * DM + h * HDIM) * S + s;
  const short* k = Kt + ((long)b * DM + h * HDIM) * S + s;
  float acc = 0.f;
#pragma unroll 8
  for (int j = 0; j < HDIM; ++j)
    acc += bf2f(q[(long)j * S]) * bf2f(k[(long)j * S]);
  logits[((long)b * NH + h) * S + s] = acc * 0.125f;
}

__global__ void k_softw(const float* __restrict__ logits, float* __restrict__ w) {
  int idx = blockIdx.x * 256 + threadIdx.x;   // b*S + s
  if (idx >= NB * S) return;
  int b = idx >> 12, s = idx & (S - 1);
  const float* lp = logits + (long)b * NH * S + s;
  float v[NH];
  float m = -1e30f;
#pragma unroll
  for (int h = 0; h < NH; ++h) { v[h] = lp[(long)h * S]; m = fmaxf(m, v[h]); }
  float sum = 0.f;
#pragma unroll
  for (int h = 0; h < NH; ++h) { v[h] = expf(v[h] - m); sum += v[h]; }
  float inv = 1.f / sum;
  float* wp = w + (long)b * NH * S + s;
#pragma unroll
  for (int h = 0; h < NH; ++h) wp[(long)h * S] = v[h] * inv;
}

__global__ void k_att(short* vt, const float* __restrict__ wsm) {
  long i8 = ((long)blockIdx.x * 256 + threadIdx.x) * 8;
  if (i8 >= (long)NB * DS) return;
  int b = (int)(i8 >> 22);
  long r = i8 & (DS - 1);
  int d = (int)(r >> 12);
  int s = (int)(r & (S - 1));
  int h = d >> 6;
  const float* wp = wsm + ((long)b * NH + h) * S + s;
  u16x8 vv = *(const u16x8*)(vt + i8);
  u16x8 ov;
#pragma unroll
  for (int j = 0; j < 8; ++j) ov[j] = f2bf(wp[j] * bf2f((short)vv[j]));
  *(u16x8*)(vt + i8) = ov;
}

// ---------------- 256x256 8-phase GEMM ----------------
// C = A @ B ; A row-major [M,K] bf16, B given TRANSPOSED as Bt [N,K] bf16, ld = K.
// BM=BN=256, BK=64, 512 threads = 8 waves (2 m x 4 n), per-wave C = 128x64.
// LDS: 2 dbuf x {A,B} x 2 k-halves of [256][32] bf16 (16KB each) = 128 KiB.
// Swizzle: byte ^= ((byte>>8)&3)<<4 (involution); staged via linear LDS dest +
// inverse-swizzled global source; reads apply the same XOR.
// EPI 0: bf16 C[M,N] (per-batch); EPI 1: bf16 transposed [b][col][s] + bias*bsc;
// EPI 2: fp32 C + bias + resid.
template <int EPI>
__global__ __launch_bounds__(512, 2) void gemm8(
    const short* __restrict__ A, const short* __restrict__ Bt,
    short* __restrict__ Cb, float* __restrict__ Cf,
    const float* __restrict__ bias, const float* __restrict__ bsc,
    const float* __restrict__ resid,
    int M, int N, int K, long aBatch, long bBatch, long cBatch) {
  __shared__ __align__(16) short As[2][2][256 * 32];   // 64 KiB
  __shared__ __align__(16) short Bs[2][2][256 * 32];   // 64 KiB

  // bijective XCD-chunked remap (nwg is always 256 here)
  const int gx = gridDim.x, gy = gridDim.y;
  const int nwg = gx * gy * gridDim.z;
  int lin = blockIdx.x + gx * (blockIdx.y + gy * blockIdx.z);
  int wg = lin;
  if ((nwg & 7) == 0) {
    const int cpx = nwg >> 3;
    wg = (lin & 7) * cpx + (lin >> 3);
  }
  const int NTN = N >> 8;
  const int ntile = wg % NTN;
  const int rest = wg / NTN;
  const int NTM = M >> 8;
  const int mtile = rest % NTM;
  const int bz = rest / NTM;

  const short* Ag = A + (long)bz * aBatch;
  const short* Bg = Bt + (long)bz * bBatch;
  const int m0 = mtile << 8, n0 = ntile << 8;
  const int tid = threadIdx.x;
  const int lane = tid & 63;
  const int wid = tid >> 6;
  const int wm = wid >> 2, wn = wid & 3;

  f32x4 acc[8][4];
#pragma unroll
  for (int i = 0; i < 8; ++i)
#pragma unroll
    for (int j = 0; j < 4; ++j) acc[i][j] = (f32x4){0.f, 0.f, 0.f, 0.f};

  const int NT = K >> 6;
  // half h: tile tau=h>>2, q=h&3: q0=A ks0, q1=B ks0, q2=A ks1, q3=B ks1
  auto stage = [&](int h) {
    const int tau = h >> 2, q = h & 3;
    const int buf = tau & 1, ks = q >> 1;
    short* ldsbase = (q & 1) ? &Bs[buf][ks][0] : &As[buf][ks][0];
    const short* gsrc = (q & 1) ? Bg : Ag;
    const int row0 = (q & 1) ? n0 : m0;
    const long k0 = (long)tau * 64 + ks * 32;
#pragma unroll
    for (int j = 0; j < 2; ++j) {
      const int o = tid * 16 + j * 8192;            // byte offset in 16KB half
      const int lo = o ^ (((o >> 8) & 3) << 4);     // inverse swizzle (involution)
      const int row = lo >> 6;
      const int cs = (lo & 63) >> 1;                // short col 0..31
      GLOAD(gsrc + (long)(row0 + row) * K + k0 + cs, (short*)((char*)ldsbase + o));
    }
  };

  // prologue: halves 0..6 (tile0 complete + tile1 A0,B0,A1), then vmcnt(6)
  for (int h = 0; h < 7; ++h) stage(h);
  asm volatile("s_waitcnt vmcnt(6)" ::: "memory");
  SBAR();

  short8 bf[4];
  for (int t = 0; t < NT; ++t) {
    const int buf = t & 1;
#pragma unroll
    for (int p = 0; p < 4; ++p) {
      const int ks = p >> 1, mh = p & 1;
      short8 af[4];
      {
        const short* Ah = &As[buf][ks][0];
        const int kb = (lane >> 4) * 16;                   // k byte offset
        const int r0 = wm * 128 + mh * 64 + (lane & 15);
#pragma unroll
        for (int i = 0; i < 4; ++i) {
          int byte = (r0 + i * 16) * 64 + kb;
          byte ^= ((byte >> 8) & 3) << 4;
          af[i] = *(const short8*)((const char*)Ah + byte);
        }
        if (mh == 0) {
          const short* Bh = &Bs[buf][ks][0];
          const int c0 = wn * 64 + (lane & 15);
#pragma unroll
          for (int j = 0; j < 4; ++j) {
            int byte = (c0 + j * 16) * 64 + kb;
            byte ^= ((byte >> 8) & 3) << 4;
            bf[j] = *(const short8*)((const char*)Bh + byte);
          }
        }
      }
      { const int h = 4 * t + p + 7; if (h < 4 * NT) stage(h); }
      SBAR();
      WAITL0();
      __builtin_amdgcn_s_setprio(1);
#pragma unroll
      for (int i = 0; i < 4; ++i)
#pragma unroll
        for (int j = 0; j < 4; ++j)
          acc[mh * 4 + i][j] = __builtin_amdgcn_mfma_f32_16x16x32_bf16(
              af[i], bf[j], acc[mh * 4 + i][j], 0, 0, 0);
      __builtin_amdgcn_s_setprio(0);
      if (p == 3) {
        if (t < NT - 2) {
          asm volatile("s_waitcnt vmcnt(6)" ::: "memory");
        } else if (t == NT - 2) {
          asm volatile("s_waitcnt vmcnt(0)" ::: "memory");
        }
      }
      SBAR();
    }
  }

  // epilogue: C/D layout col = lane&15, row = (lane>>4)*4 + reg
  const int rl = (lane >> 4) << 2;
#pragma unroll
  for (int f = 0; f < 8; ++f) {
    const int rbase = m0 + wm * 128 + f * 16 + rl;
#pragma unroll
    for (int j = 0; j < 4; ++j) {
      const int col = n0 + wn * 64 + j * 16 + (lane & 15);
      f32x4 a = acc[f][j];
      if constexpr (EPI == 0) {
        short* cp = Cb + (long)bz * cBatch;
#pragma unroll
        for (int r = 0; r < 4; ++r)
          cp[(long)(rbase + r) * N + col] = (short)f2bf(a[r]);
      } else if constexpr (EPI == 1) {
        float sc = bsc ? bsc[0] : 1.f;
        float bi = bias ? bias[col] * sc : 0.f;
        int b_ = rbase >> 12;
        int s_ = rbase & (S - 1);
        long addr = ((long)(b_ * DM + col)) * S + s_;
        u16x4 pk;
#pragma unroll
        for (int r = 0; r < 4; ++r) pk[r] = f2bf(a[r] + bi);
        *(u16x4*)(Cb + addr) = pk;
      } else {
        float bi = bias[col];
#pragma unroll
        for (int r = 0; r < 4; ++r) {
          long o = (long)(rbase + r) * N + col;
          Cf[o] = a[r] + bi + resid[o];
        }
      }
    }
  }
}

// ---------------- launch ----------------
extern "C" void kernel_launch(void* const* d_in, const int* in_sizes, int n_in,
                              void* d_out, int out_size, void* d_ws, size_t ws_size,
                              hipStream_t stream) {
  const float* x     = (const float*)d_in[0];
  const float* fd    = (const float*)d_in[1];
  const float* Wq    = (const float*)d_in[2];
  const float* bq    = (const float*)d_in[3];
  const float* Wk    = (const float*)d_in[4];
  const float* bk    = (const float*)d_in[5];
  const float* Wv    = (const float*)d_in[6];
  const float* bv    = (const float*)d_in[7];
  const float* Wo    = (const float*)d_in[8];
  const float* bo    = (const float*)d_in[9];
  const float* alpha = (const float*)d_in[10];
  const float* fsc   = (const float*)d_in[11];
  float* out = (float*)d_out;

  // --- workspace layout (~106.5 MB total) ---
  char* wp = (char*)d_ws;
  auto alloc = [&](size_t bytes) {
    char* p = wp;
    wp += (bytes + 255) & ~(size_t)255;
    return p;
  };
  float* cos_tab = (float*)alloc(S * 4);
  float* c_arr   = (float*)alloc(S * 4);          // c_arr[0] = c0 bias factor
  float* g       = (float*)alloc(S * 4);
  float* logits  = (float*)alloc((size_t)NB * NH * S * 4);   // 1 MB
  float* wsm     = (float*)alloc((size_t)NB * NH * S * 4);   // 1 MB
  short* WqT = (short*)alloc((size_t)DM * DM * 2);           // 2 MB each
  short* WkT = (short*)alloc((size_t)DM * DM * 2);
  short* WvT = (short*)alloc((size_t)DM * DM * 2);
  short* WoT = (short*)alloc((size_t)DM * DM * 2);
  short* slotA = (short*)alloc((size_t)NB * DS * 2);  // 32 MB: XbT -> Vt/att
  short* slotB = (short*)alloc((size_t)NB * DS * 2);  // 32 MB: G   -> Mc
  short* slotC = (short*)alloc((size_t)NB * DS * 2);  // 32 MB: Xs  -> att_time

  // d_out as scratch until the final GEMM (written fully before each read)
  short* QtT = (short*)d_out;
  short* KtT = (short*)d_out + (size_t)2 * DS;

  short* XbT = slotA;
  short* Gm  = slotB;
  short* Xs  = slotC;
  short* VtT = slotA;
  short* Mc  = slotB;
  short* att_time = slotC;

  dim3 blk(256), blk8(512);

  // tables + transform matrix
  k_tables<<<dim3(S / 256), blk, 0, stream>>>(fd, alpha, fsc, cos_tab, c_arr);
  k_g<<<dim3(S / 256), blk, 0, stream>>>(cos_tab, c_arr, g);
  k_buildG<<<dim3((unsigned)((long)S * S / 8 / 256)), blk, 0, stream>>>(g, Gm);

  // casts / transpose
  k_castWT<<<dim3(DM * DM / 256), blk, 0, stream>>>(Wq, WqT);
  k_castWT<<<dim3(DM * DM / 256), blk, 0, stream>>>(Wk, WkT);
  k_castWT<<<dim3(DM * DM / 256), blk, 0, stream>>>(Wv, WvT);
  k_castWT<<<dim3(DM * DM / 256), blk, 0, stream>>>(Wo, WoT);
  k_transX<<<dim3(S / 64, DM / 64, NB), blk, 0, stream>>>(x, XbT);

  // Xs_b = G @ X_b  (spectral applied ONCE, before projections)  [b][s][d] bf16
  dim3 gspec(DM / 256, S / 256, NB);     // (NTN, NTM, batch) = (4,16,4) = 256 wg
  gemm8<0><<<gspec, blk8, 0, stream>>>(Gm, XbT, Xs, nullptr, nullptr, nullptr, nullptr,
                                       S, DM, S, 0, DS, DS);

  // q_t/k_t/v_t = Xs @ W + c0*b, written transposed [b][d][s]
  dim3 gproj(DM / 256, MTOT / 256, 1);   // (4,64,1) = 256 wg
  gemm8<1><<<gproj, blk8, 0, stream>>>(Xs, WqT, QtT, nullptr, bq, c_arr, nullptr,
                                       MTOT, DM, DM, 0, 0, 0);
  gemm8<1><<<gproj, blk8, 0, stream>>>(Xs, WkT, KtT, nullptr, bk, c_arr, nullptr,
                                       MTOT, DM, DM, 0, 0, 0);
  gemm8<1><<<gproj, blk8, 0, stream>>>(Xs, WvT, VtT, nullptr, bv, c_arr, nullptr,
                                       MTOT, DM, DM, 0, 0, 0);

  // logits, softmax over heads, attended (in-place on v_t)
  k_logits<<<dim3(S / 256, NH, NB), blk, 0, stream>>>(QtT, KtT, logits);
  k_softw<<<dim3(NB * S / 256), blk, 0, stream>>>(logits, wsm);
  k_att<<<dim3((unsigned)((long)NB * DS / 8 / 256)), blk, 0, stream>>>(VtT, wsm);

  // Mc (re-using Gm slot), then attended_time_b = Mc @ att_b -> [b][s][d]
  k_buildM<<<dim3((unsigned)((long)S * S / 8 / 256)), blk, 0, stream>>>(cos_tab, Mc);
  gemm8<0><<<gspec, blk8, 0, stream>>>(Mc, VtT, att_time, nullptr, nullptr, nullptr, nullptr,
                                       S, DM, S, 0, DS, DS);

  // out = att_time @ Wo + bo + x   (fp32; d_out scratch fully dead by now)
  gemm8<2><<<gproj, blk8, 0, stream>>>(att_time, WoT, nullptr, out, bo, nullptr, x,
                                       MTOT, DM, DM, 0, 0, 0);
}

// Round 4
// 619.989 us; speedup vs baseline: 1.2765x; 1.0264x over previous
//
#include <hip/hip_runtime.h>

// ---------------- constants ----------------
#define S      4096
#define DM     1024
#define NB     4
#define NH     16
#define HDIM   64
#define MTOT   (NB * S)          // 16384
#define DS     ((long)DM * S)    // 4,194,304

typedef __attribute__((ext_vector_type(8))) short short8;
typedef __attribute__((ext_vector_type(4))) float f32x4;
typedef __attribute__((ext_vector_type(8))) unsigned short u16x8;
typedef __attribute__((ext_vector_type(4))) unsigned short u16x4;

__device__ __forceinline__ unsigned short f2bf(float f) {
  union { float f; unsigned u; } v; v.f = f;
  unsigned r = v.u + 0x7fffu + ((v.u >> 16) & 1u);   // RNE
  return (unsigned short)(r >> 16);
}
__device__ __forceinline__ float bf2f(short h) {
  union { unsigned u; float f; } v; v.u = ((unsigned)(unsigned short)h) << 16;
  return v.f;
}

#define GLOAD(gp, lp) __builtin_amdgcn_global_load_lds( \
    (const __attribute__((address_space(1))) void*)(gp), \
    (__attribute__((address_space(3))) void*)(lp), 16, 0, 0)

#define SBAR() do { asm volatile("" ::: "memory"); __builtin_amdgcn_s_barrier(); \
                    asm volatile("" ::: "memory"); } while (0)
#define WAITL0() asm volatile("s_waitcnt lgkmcnt(0)" ::: "memory")

// LDS swizzle for 64B-row tiles: XOR byte bits 4-5 with row bits 1-2 (byte bits 7-8).
// Involution; key bits outside target -> both-sides consistent.
#define SWZ(o) ((o) ^ ((((o) >> 7) & 3) << 4))

// ---------------- small kernels (unchanged, verified in R2) ----------------

__global__ void k_tables(const float* __restrict__ fd, const float* __restrict__ alpha,
                         const float* __restrict__ fsc,
                         float* __restrict__ cos_tab, float* __restrict__ c_arr) {
  int k = blockIdx.x * 256 + threadIdx.x;
  if (k >= S) return;
  float aa = alpha[0] + fsc[0] * (fd[0] - 1.5f);
  const float twopi = 6.28318530717958647692f;
  cos_tab[k] = cosf(twopi * ((float)k / (float)S));
  int kk = (k <= S / 2) ? k : (S - k);
  float af = (float)kk / (float)S;
  c_arr[k] = cosf(aa * atanf(logf(af + 1e-10f)));
}

__global__ void k_g(const float* __restrict__ cos_tab, const float* __restrict__ c_arr,
                    float* __restrict__ g) {
  __shared__ float sct[S];
  __shared__ float sc[S];
  for (int i = threadIdx.x; i < S; i += 256) { sct[i] = cos_tab[i]; sc[i] = c_arr[i]; }
  __syncthreads();
  int j = blockIdx.x * 256 + threadIdx.x;
  float acc = 0.f;
  int t = 0;
  for (int k = 0; k < S; ++k) {
    acc += sc[k] * sct[t];
    t = (t + j) & (S - 1);
  }
  g[j] = acc * (1.f / (float)S);
}

__global__ void k_buildG(const float* __restrict__ g, short* __restrict__ G) {
  long i8 = ((long)blockIdx.x * 256 + threadIdx.x) * 8;
  if (i8 >= (long)S * S) return;
  int n = (int)(i8 >> 12);
  int m = (int)(i8 & (S - 1));
  u16x8 gv;
#pragma unroll
  for (int j = 0; j < 8; ++j) gv[j] = f2bf(g[(n - m - j) & (S - 1)]);
  *(u16x8*)(G + i8) = gv;
}

__global__ void k_buildM(const float* __restrict__ cos_tab, short* __restrict__ Mc) {
  long i8 = ((long)blockIdx.x * 256 + threadIdx.x) * 8;
  if (i8 >= (long)S * S) return;
  int n = (int)(i8 >> 12);
  int m = (int)(i8 & (S - 1));
  u16x8 mv;
#pragma unroll
  for (int j = 0; j < 8; ++j) mv[j] = f2bf(cos_tab[(n * (m + j)) & (S - 1)] * 0.015625f);
  *(u16x8*)(Mc + i8) = mv;
}

__global__ void k_castWT(const float* __restrict__ W, short* __restrict__ WT) {
  int idx = blockIdx.x * 256 + threadIdx.x;
  if (idx >= DM * DM) return;
  int nrow = idx >> 10, kcol = idx & (DM - 1);
  WT[idx] = (short)f2bf(W[kcol * DM + nrow]);
}

__global__ void k_transX(const float* __restrict__ x, short* __restrict__ xt) {
  __shared__ float tile[64][65];
  int s0 = blockIdx.x * 64, d0 = blockIdx.y * 64, b = blockIdx.z;
  int t = threadIdx.x;
  int r = t >> 4, c4 = (t & 15) * 4;
  const float* xp = x + ((long)(b * S + s0) * DM) + d0;
#pragma unroll
  for (int rr = 0; rr < 4; ++rr) {
    float4 v = *(const float4*)(xp + (long)(r + rr * 16) * DM + c4);
    tile[r + rr * 16][c4 + 0] = v.x;
    tile[r + rr * 16][c4 + 1] = v.y;
    tile[r + rr * 16][c4 + 2] = v.z;
    tile[r + rr * 16][c4 + 3] = v.w;
  }
  __syncthreads();
  int s_loc = t & 63, dq = t >> 6;
  short* op = xt + ((long)(b * DM + d0) * S) + s0;
#pragma unroll
  for (int i = 0; i < 16; ++i) {
    int d_loc = dq * 16 + i;
    op[(long)d_loc * S + s_loc] = (short)f2bf(tile[s_loc][d_loc]);
  }
}

__global__ void k_logits(const short* __restrict__ Qt, const short* __restrict__ Kt,
                         float* __restrict__ logits) {
  int s = blockIdx.x * 256 + threadIdx.x;
  int h = blockIdx.y, b = blockIdx.z;
  const short* q = Qt + ((long)b * DM + h * HDIM) * S + s;
  const short* k = Kt + ((long)b * DM + h * HDIM) * S + s;
  float acc = 0.f;
#pragma unroll 8
  for (int j = 0; j < HDIM; ++j)
    acc += bf2f(q[(long)j * S]) * bf2f(k[(long)j * S]);
  logits[((long)b * NH + h) * S + s] = acc * 0.125f;
}

__global__ void k_softw(const float* __restrict__ logits, float* __restrict__ w) {
  int idx = blockIdx.x * 256 + threadIdx.x;   // b*S + s
  if (idx >= NB * S) return;
  int b = idx >> 12, s = idx & (S - 1);
  const float* lp = logits + (long)b * NH * S + s;
  float v[NH];
  float m = -1e30f;
#pragma unroll
  for (int h = 0; h < NH; ++h) { v[h] = lp[(long)h * S]; m = fmaxf(m, v[h]); }
  float sum = 0.f;
#pragma unroll
  for (int h = 0; h < NH; ++h) { v[h] = expf(v[h] - m); sum += v[h]; }
  float inv = 1.f / sum;
  float* wp = w + (long)b * NH * S + s;
#pragma unroll
  for (int h = 0; h < NH; ++h) wp[(long)h * S] = v[h] * inv;
}

__global__ void k_att(short* vt, const float* __restrict__ wsm) {
  long i8 = ((long)blockIdx.x * 256 + threadIdx.x) * 8;
  if (i8 >= (long)NB * DS) return;
  int b = (int)(i8 >> 22);
  long r = i8 & (DS - 1);
  int d = (int)(r >> 12);
  int s = (int)(r & (S - 1));
  int h = d >> 6;
  const float* wp = wsm + ((long)b * NH + h) * S + s;
  u16x8 vv = *(const u16x8*)(vt + i8);
  u16x8 ov;
#pragma unroll
  for (int j = 0; j < 8; ++j) ov[j] = f2bf(wp[j] * bf2f((short)vv[j]));
  *(u16x8*)(vt + i8) = ov;
}

// ---------------- 256x256 8-phase GEMM ----------------
// C = A @ B ; A row-major [M,K] bf16, B given TRANSPOSED as Bt [N,K] bf16, ld = K.
// BM=BN=256, BK=64, 512 threads = 8 waves (2 m x 4 n), per-wave C = 128x64.
// LDS: 2 dbuf x {A,B} x 2 k-halves of [256][32] bf16 (16KB each) = 128 KiB.
// Swizzle SWZ (row bits 1-2 -> byte bits 4-5): staged via linear LDS dest +
// inverse-swizzled global source; reads apply the same XOR.
// EPI 0: bf16 C[M,N] (per-batch); EPI 1: bf16 transposed [b][col][s] + bias*bsc;
// EPI 2: fp32 C + bias + resid.
template <int EPI>
__global__ __launch_bounds__(512, 2) void gemm8(
    const short* __restrict__ A, const short* __restrict__ Bt,
    short* __restrict__ Cb, float* __restrict__ Cf,
    const float* __restrict__ bias, const float* __restrict__ bsc,
    const float* __restrict__ resid,
    int M, int N, int K, long aBatch, long bBatch, long cBatch) {
  __shared__ __align__(16) short As[2][2][256 * 32];   // 64 KiB
  __shared__ __align__(16) short Bs[2][2][256 * 32];   // 64 KiB

  // bijective XCD-chunked remap (nwg is always 256 here)
  const int gx = gridDim.x, gy = gridDim.y;
  const int nwg = gx * gy * gridDim.z;
  int lin = blockIdx.x + gx * (blockIdx.y + gy * blockIdx.z);
  int wg = lin;
  if ((nwg & 7) == 0) {
    const int cpx = nwg >> 3;
    wg = (lin & 7) * cpx + (lin >> 3);
  }
  const int NTN = N >> 8;
  const int ntile = wg % NTN;
  const int rest = wg / NTN;
  const int NTM = M >> 8;
  const int mtile = rest % NTM;
  const int bz = rest / NTM;

  const short* Ag = A + (long)bz * aBatch;
  const short* Bg = Bt + (long)bz * bBatch;
  const int m0 = mtile << 8, n0 = ntile << 8;
  const int tid = threadIdx.x;
  const int lane = tid & 63;
  const int wid = tid >> 6;
  const int wm = wid >> 2, wn = wid & 3;

  f32x4 acc[8][4];
#pragma unroll
  for (int i = 0; i < 8; ++i)
#pragma unroll
    for (int j = 0; j < 4; ++j) acc[i][j] = (f32x4){0.f, 0.f, 0.f, 0.f};

  const int NT = K >> 6;
  // half h: tile tau=h>>2, q=h&3: q0=A ks0, q1=B ks0, q2=A ks1, q3=B ks1
  auto stage = [&](int h) {
    const int tau = h >> 2, q = h & 3;
    const int buf = tau & 1, ks = q >> 1;
    short* ldsbase = (q & 1) ? &Bs[buf][ks][0] : &As[buf][ks][0];
    const short* gsrc = (q & 1) ? Bg : Ag;
    const int row0 = (q & 1) ? n0 : m0;
    const long k0 = (long)tau * 64 + ks * 32;
#pragma unroll
    for (int j = 0; j < 2; ++j) {
      const int o = tid * 16 + j * 8192;            // byte offset in 16KB half
      const int lo = SWZ(o);                        // inverse swizzle (involution)
      const int row = lo >> 6;
      const int cs = (lo & 63) >> 1;                // short col 0..31
      GLOAD(gsrc + (long)(row0 + row) * K + k0 + cs, (short*)((char*)ldsbase + o));
    }
  };

  // prologue: halves 0..6 (tile0 complete + tile1 A0,B0,A1), then vmcnt(6)
  for (int h = 0; h < 7; ++h) stage(h);
  asm volatile("s_waitcnt vmcnt(6)" ::: "memory");
  SBAR();

  short8 bf[4];
  for (int t = 0; t < NT; ++t) {
    const int buf = t & 1;
#pragma unroll
    for (int p = 0; p < 4; ++p) {
      const int ks = p >> 1, mh = p & 1;
      short8 af[4];
      {
        const short* Ah = &As[buf][ks][0];
        const int kb = (lane >> 4) * 16;                   // k byte offset
        const int r0 = wm * 128 + mh * 64 + (lane & 15);
#pragma unroll
        for (int i = 0; i < 4; ++i) {
          int byte = (r0 + i * 16) * 64 + kb;
          byte = SWZ(byte);
          af[i] = *(const short8*)((const char*)Ah + byte);
        }
        if (mh == 0) {
          const short* Bh = &Bs[buf][ks][0];
          const int c0 = wn * 64 + (lane & 15);
#pragma unroll
          for (int j = 0; j < 4; ++j) {
            int byte = (c0 + j * 16) * 64 + kb;
            byte = SWZ(byte);
            bf[j] = *(const short8*)((const char*)Bh + byte);
          }
        }
      }
      { const int h = 4 * t + p + 7; if (h < 4 * NT) stage(h); }
      SBAR();
      WAITL0();
      __builtin_amdgcn_s_setprio(1);
#pragma unroll
      for (int i = 0; i < 4; ++i)
#pragma unroll
        for (int j = 0; j < 4; ++j)
          acc[mh * 4 + i][j] = __builtin_amdgcn_mfma_f32_16x16x32_bf16(
              af[i], bf[j], acc[mh * 4 + i][j], 0, 0, 0);
      __builtin_amdgcn_s_setprio(0);
      if (p == 3) {
        if (t < NT - 2) {
          asm volatile("s_waitcnt vmcnt(6)" ::: "memory");
        } else if (t == NT - 2) {
          asm volatile("s_waitcnt vmcnt(0)" ::: "memory");
        }
      }
      SBAR();
    }
  }

  // epilogue: C/D layout col = lane&15, row = (lane>>4)*4 + reg
  const int rl = (lane >> 4) << 2;
#pragma unroll
  for (int f = 0; f < 8; ++f) {
    const int rbase = m0 + wm * 128 + f * 16 + rl;
#pragma unroll
    for (int j = 0; j < 4; ++j) {
      const int col = n0 + wn * 64 + j * 16 + (lane & 15);
      f32x4 a = acc[f][j];
      if constexpr (EPI == 0) {
        short* cp = Cb + (long)bz * cBatch;
#pragma unroll
        for (int r = 0; r < 4; ++r)
          cp[(long)(rbase + r) * N + col] = (short)f2bf(a[r]);
      } else if constexpr (EPI == 1) {
        float sc = bsc ? bsc[0] : 1.f;
        float bi = bias ? bias[col] * sc : 0.f;
        int b_ = rbase >> 12;
        int s_ = rbase & (S - 1);
        long addr = ((long)(b_ * DM + col)) * S + s_;
        u16x4 pk;
#pragma unroll
        for (int r = 0; r < 4; ++r) pk[r] = f2bf(a[r] + bi);
        *(u16x4*)(Cb + addr) = pk;
      } else {
        float bi = bias[col];
#pragma unroll
        for (int r = 0; r < 4; ++r) {
          long o = (long)(rbase + r) * N + col;
          Cf[o] = a[r] + bi + resid[o];
        }
      }
    }
  }
}

// ---------------- launch ----------------
extern "C" void kernel_launch(void* const* d_in, const int* in_sizes, int n_in,
                              void* d_out, int out_size, void* d_ws, size_t ws_size,
                              hipStream_t stream) {
  const float* x     = (const float*)d_in[0];
  const float* fd    = (const float*)d_in[1];
  const float* Wq    = (const float*)d_in[2];
  const float* bq    = (const float*)d_in[3];
  const float* Wk    = (const float*)d_in[4];
  const float* bk    = (const float*)d_in[5];
  const float* Wv    = (const float*)d_in[6];
  const float* bv    = (const float*)d_in[7];
  const float* Wo    = (const float*)d_in[8];
  const float* bo    = (const float*)d_in[9];
  const float* alpha = (const float*)d_in[10];
  const float* fsc   = (const float*)d_in[11];
  float* out = (float*)d_out;

  // --- workspace layout (~106.5 MB total) ---
  char* wp = (char*)d_ws;
  auto alloc = [&](size_t bytes) {
    char* p = wp;
    wp += (bytes + 255) & ~(size_t)255;
    return p;
  };
  float* cos_tab = (float*)alloc(S * 4);
  float* c_arr   = (float*)alloc(S * 4);          // c_arr[0] = c0 bias factor
  float* g       = (float*)alloc(S * 4);
  float* logits  = (float*)alloc((size_t)NB * NH * S * 4);   // 1 MB
  float* wsm     = (float*)alloc((size_t)NB * NH * S * 4);   // 1 MB
  short* WqT = (short*)alloc((size_t)DM * DM * 2);           // 2 MB each
  short* WkT = (short*)alloc((size_t)DM * DM * 2);
  short* WvT = (short*)alloc((size_t)DM * DM * 2);
  short* WoT = (short*)alloc((size_t)DM * DM * 2);
  short* slotA = (short*)alloc((size_t)NB * DS * 2);  // 32 MB: XbT -> Vt/att
  short* slotB = (short*)alloc((size_t)NB * DS * 2);  // 32 MB: G   -> Mc
  short* slotC = (short*)alloc((size_t)NB * DS * 2);  // 32 MB: Xs  -> att_time

  // d_out as scratch until the final GEMM (written fully before each read)
  short* QtT = (short*)d_out;
  short* KtT = (short*)d_out + (size_t)2 * DS;

  short* XbT = slotA;
  short* Gm  = slotB;
  short* Xs  = slotC;
  short* VtT = slotA;
  short* Mc  = slotB;
  short* att_time = slotC;

  dim3 blk(256), blk8(512);

  // tables + transform matrix
  k_tables<<<dim3(S / 256), blk, 0, stream>>>(fd, alpha, fsc, cos_tab, c_arr);
  k_g<<<dim3(S / 256), blk, 0, stream>>>(cos_tab, c_arr, g);
  k_buildG<<<dim3((unsigned)((long)S * S / 8 / 256)), blk, 0, stream>>>(g, Gm);

  // casts / transpose
  k_castWT<<<dim3(DM * DM / 256), blk, 0, stream>>>(Wq, WqT);
  k_castWT<<<dim3(DM * DM / 256), blk, 0, stream>>>(Wk, WkT);
  k_castWT<<<dim3(DM * DM / 256), blk, 0, stream>>>(Wv, WvT);
  k_castWT<<<dim3(DM * DM / 256), blk, 0, stream>>>(Wo, WoT);
  k_transX<<<dim3(S / 64, DM / 64, NB), blk, 0, stream>>>(x, XbT);

  // Xs_b = G @ X_b  (spectral applied ONCE, before projections)  [b][s][d] bf16
  dim3 gspec(DM / 256, S / 256, NB);     // (NTN, NTM, batch) = (4,16,4) = 256 wg
  gemm8<0><<<gspec, blk8, 0, stream>>>(Gm, XbT, Xs, nullptr, nullptr, nullptr, nullptr,
                                       S, DM, S, 0, DS, DS);

  // q_t/k_t/v_t = Xs @ W + c0*b, written transposed [b][d][s]
  dim3 gproj(DM / 256, MTOT / 256, 1);   // (4,64,1) = 256 wg
  gemm8<1><<<gproj, blk8, 0, stream>>>(Xs, WqT, QtT, nullptr, bq, c_arr, nullptr,
                                       MTOT, DM, DM, 0, 0, 0);
  gemm8<1><<<gproj, blk8, 0, stream>>>(Xs, WkT, KtT, nullptr, bk, c_arr, nullptr,
                                       MTOT, DM, DM, 0, 0, 0);
  gemm8<1><<<gproj, blk8, 0, stream>>>(Xs, WvT, VtT, nullptr, bv, c_arr, nullptr,
                                       MTOT, DM, DM, 0, 0, 0);

  // logits, softmax over heads, attended (in-place on v_t)
  k_logits<<<dim3(S / 256, NH, NB), blk, 0, stream>>>(QtT, KtT, logits);
  k_softw<<<dim3(NB * S / 256), blk, 0, stream>>>(logits, wsm);
  k_att<<<dim3((unsigned)((long)NB * DS / 8 / 256)), blk, 0, stream>>>(VtT, wsm);

  // Mc (re-using Gm slot), then attended_time_b = Mc @ att_b -> [b][s][d]
  k_buildM<<<dim3((unsigned)((long)S * S / 8 / 256)), blk, 0, stream>>>(cos_tab, Mc);
  gemm8<0><<<gspec, blk8, 0, stream>>>(Mc, VtT, att_time, nullptr, nullptr, nullptr, nullptr,
                                       S, DM, S, 0, DS, DS);

  // out = att_time @ Wo + bo + x   (fp32; d_out scratch fully dead by now)
  gemm8<2><<<gproj, blk8, 0, stream>>>(att_time, WoT, nullptr, out, bo, nullptr, x,
                                       MTOT, DM, DM, 0, 0, 0);
}

// Round 5
// 541.779 us; speedup vs baseline: 1.4608x; 1.1444x over previous
//
#include <hip/hip_runtime.h>

// ---------------- constants ----------------
#define S      4096
#define DM     1024
#define NB     4
#define NH     16
#define HDIM   64
#define MTOT   (NB * S)          // 16384
#define DS     ((long)DM * S)    // 4,194,304
#define MH     2304              // padded half-rows (2049 used), mult of 256
#define KH     2112              // folded K (2049 used), mult of 64

typedef __attribute__((ext_vector_type(8))) short short8;
typedef __attribute__((ext_vector_type(4))) float f32x4;
typedef __attribute__((ext_vector_type(8))) unsigned short u16x8;
typedef __attribute__((ext_vector_type(4))) unsigned short u16x4;

__device__ __forceinline__ unsigned short f2bf(float f) {
  union { float f; unsigned u; } v; v.f = f;
  unsigned r = v.u + 0x7fffu + ((v.u >> 16) & 1u);   // RNE
  return (unsigned short)(r >> 16);
}
__device__ __forceinline__ float bf2f(short h) {
  union { unsigned u; float f; } v; v.u = ((unsigned)(unsigned short)h) << 16;
  return v.f;
}

#define GLOAD(gp, lp) __builtin_amdgcn_global_load_lds( \
    (const __attribute__((address_space(1))) void*)(gp), \
    (__attribute__((address_space(3))) void*)(lp), 16, 0, 0)

#define SBAR() do { asm volatile("" ::: "memory"); __builtin_amdgcn_s_barrier(); \
                    asm volatile("" ::: "memory"); } while (0)
#define WAITL0() asm volatile("s_waitcnt lgkmcnt(0)" ::: "memory")

// LDS swizzle for 64B-row tiles: XOR byte bits 4-5 with row bits 1-2 (byte bits 7-8).
#define SWZ(o) ((o) ^ ((((o) >> 7) & 3) << 4))

// ---------------- small kernels ----------------

__global__ void k_tables(const float* __restrict__ fd, const float* __restrict__ alpha,
                         const float* __restrict__ fsc,
                         float* __restrict__ cos_tab, float* __restrict__ c_arr) {
  int k = blockIdx.x * 256 + threadIdx.x;
  if (k >= S) return;
  float aa = alpha[0] + fsc[0] * (fd[0] - 1.5f);
  const float twopi = 6.28318530717958647692f;
  cos_tab[k] = cosf(twopi * ((float)k / (float)S));
  int kk = (k <= S / 2) ? k : (S - k);
  float af = (float)kk / (float)S;
  c_arr[k] = cosf(aa * atanf(logf(af + 1e-10f)));
}

__global__ void k_g(const float* __restrict__ cos_tab, const float* __restrict__ c_arr,
                    float* __restrict__ g) {
  __shared__ float sct[S];
  __shared__ float sc[S];
  for (int i = threadIdx.x; i < S; i += 256) { sct[i] = cos_tab[i]; sc[i] = c_arr[i]; }
  __syncthreads();
  int j = blockIdx.x * 256 + threadIdx.x;
  float acc = 0.f;
  int t = 0;
  for (int k = 0; k < S; ++k) {
    acc += sc[k] * sct[t];
    t = (t + j) & (S - 1);
  }
  g[j] = acc * (1.f / (float)S);
}

__global__ void k_buildG(const float* __restrict__ g, short* __restrict__ G) {
  long i8 = ((long)blockIdx.x * 256 + threadIdx.x) * 8;
  if (i8 >= (long)S * S) return;
  int n = (int)(i8 >> 12);
  int m = (int)(i8 & (S - 1));
  u16x8 gv;
#pragma unroll
  for (int j = 0; j < 8; ++j) gv[j] = f2bf(g[(n - m - j) & (S - 1)]);
  *(u16x8*)(G + i8) = gv;
}

// Mc2[n][m] (n<MH, m<KH, ld KH): (m<=2048) ? cos(2*pi*n*m/S)/64 : 0
__global__ void k_buildM2(const float* __restrict__ cos_tab, short* __restrict__ Mc2) {
  long i8 = ((long)blockIdx.x * 256 + threadIdx.x) * 8;
  if (i8 >= (long)MH * KH) return;
  int n = (int)(i8 / KH);
  int m = (int)(i8 % KH);          // KH%8==0 -> no row straddle
  u16x8 mv;
#pragma unroll
  for (int j = 0; j < 8; ++j) {
    int mm = m + j;
    float vv = (mm <= 2048) ? cos_tab[(n * mm) & (S - 1)] * 0.015625f : 0.f;
    mv[j] = f2bf(vv);
  }
  *(u16x8*)(Mc2 + i8) = mv;
}

// W [K][N] fp32 -> WT [N][K] bf16, tiled coalesced transpose
__global__ void k_transW(const float* __restrict__ W, short* __restrict__ WT) {
  __shared__ float tile[64][65];
  int k0 = blockIdx.x * 64, n0 = blockIdx.y * 64;
  int t = threadIdx.x;
  int r = t >> 4, c4 = (t & 15) * 4;
  const float* ip = W + (long)k0 * DM + n0;
#pragma unroll
  for (int rr = 0; rr < 4; ++rr) {
    float4 v = *(const float4*)(ip + (long)(r + rr * 16) * DM + c4);
    tile[r + rr * 16][c4 + 0] = v.x;
    tile[r + rr * 16][c4 + 1] = v.y;
    tile[r + rr * 16][c4 + 2] = v.z;
    tile[r + rr * 16][c4 + 3] = v.w;
  }
  __syncthreads();
  int k_loc = t & 63, nq = t >> 6;
  short* op = WT + (long)n0 * DM + k0;
#pragma unroll
  for (int i = 0; i < 16; ++i) {
    int n_loc = nq * 16 + i;
    op[(long)n_loc * DM + k_loc] = (short)f2bf(tile[k_loc][n_loc]);
  }
}

__global__ void k_transX(const float* __restrict__ x, short* __restrict__ xt) {
  __shared__ float tile[64][65];
  int s0 = blockIdx.x * 64, d0 = blockIdx.y * 64, b = blockIdx.z;
  int t = threadIdx.x;
  int r = t >> 4, c4 = (t & 15) * 4;
  const float* xp = x + ((long)(b * S + s0) * DM) + d0;
#pragma unroll
  for (int rr = 0; rr < 4; ++rr) {
    float4 v = *(const float4*)(xp + (long)(r + rr * 16) * DM + c4);
    tile[r + rr * 16][c4 + 0] = v.x;
    tile[r + rr * 16][c4 + 1] = v.y;
    tile[r + rr * 16][c4 + 2] = v.z;
    tile[r + rr * 16][c4 + 3] = v.w;
  }
  __syncthreads();
  int s_loc = t & 63, dq = t >> 6;
  short* op = xt + ((long)(b * DM + d0) * S) + s0;
#pragma unroll
  for (int i = 0; i < 16; ++i) {
    int d_loc = dq * 16 + i;
    op[(long)d_loc * S + s_loc] = (short)f2bf(tile[s_loc][d_loc]);
  }
}

__global__ void k_logits(const short* __restrict__ Qt, const short* __restrict__ Kt,
                         float* __restrict__ logits) {
  int s = blockIdx.x * 256 + threadIdx.x;
  int h = blockIdx.y, b = blockIdx.z;
  const short* q = Qt + ((long)b * DM + h * HDIM) * S + s;
  const short* k = Kt + ((long)b * DM + h * HDIM) * S + s;
  float acc = 0.f;
#pragma unroll 8
  for (int j = 0; j < HDIM; ++j)
    acc += bf2f(q[(long)j * S]) * bf2f(k[(long)j * S]);
  logits[((long)b * NH + h) * S + s] = acc * 0.125f;
}

__global__ void k_softw(const float* __restrict__ logits, float* __restrict__ w) {
  int idx = blockIdx.x * 256 + threadIdx.x;   // b*S + s
  if (idx >= NB * S) return;
  int b = idx >> 12, s = idx & (S - 1);
  const float* lp = logits + (long)b * NH * S + s;
  float v[NH];
  float m = -1e30f;
#pragma unroll
  for (int h = 0; h < NH; ++h) { v[h] = lp[(long)h * S]; m = fmaxf(m, v[h]); }
  float sum = 0.f;
#pragma unroll
  for (int h = 0; h < NH; ++h) { v[h] = expf(v[h] - m); sum += v[h]; }
  float inv = 1.f / sum;
  float* wp = w + (long)b * NH * S + s;
#pragma unroll
  for (int h = 0; h < NH; ++h) wp[(long)h * S] = v[h] * inv;
}

__global__ void k_att(short* vt, const float* __restrict__ wsm) {
  long i8 = ((long)blockIdx.x * 256 + threadIdx.x) * 8;
  if (i8 >= (long)NB * DS) return;
  int b = (int)(i8 >> 22);
  long r = i8 & (DS - 1);
  int d = (int)(r >> 12);
  int s = (int)(r & (S - 1));
  int h = d >> 6;
  const float* wp = wsm + ((long)b * NH + h) * S + s;
  u16x8 vv = *(const u16x8*)(vt + i8);
  u16x8 ov;
#pragma unroll
  for (int j = 0; j < 8; ++j) ov[j] = f2bf(wp[j] * bf2f((short)vv[j]));
  *(u16x8*)(vt + i8) = ov;
}

// A2t[b][d][m] (ld KH): m=0 -> att[b][d][0]; 1<=m<2048 -> att[m]+att[4096-m];
// m==2048 -> att[2048]; m>2048 -> 0.   (exact column-fold of the ifft cos matrix)
__global__ void k_fold(const short* __restrict__ att, short* __restrict__ A2t) {
  int m = blockIdx.x * 256 + threadIdx.x;
  if (m >= KH) return;
  int d = blockIdx.y, b = blockIdx.z;
  const short* ap = att + ((long)b * DM + d) * S;
  float v;
  if (m == 0) v = bf2f(ap[0]);
  else if (m < 2048) v = bf2f(ap[m]) + bf2f(ap[4096 - m]);
  else if (m == 2048) v = bf2f(ap[2048]);
  else v = 0.f;
  A2t[((long)b * DM + d) * KH + m] = (short)f2bf(v);
}

// ---------------- 256x256 8-phase GEMM ----------------
// C = A @ B ; A row-major [M,K] bf16, B given TRANSPOSED as Bt [N,K] bf16, ld = K.
// AMIR: A rows are read through the even-symmetry mirror: global row r -> batch
// b_=r>>12, s=r&4095, sm=min(s,4096-s); A row = A + (b_*MH + sm)*K  (att_time_half).
// EPI 0: bf16 C[M,N] (per-batch); EPI 1: bf16 transposed [b][col][s] + bias*bsc;
// EPI 2: fp32 C + bias + resid.
template <int EPI, int AMIR = 0>
__global__ __launch_bounds__(512, 2) void gemm8(
    const short* __restrict__ A, const short* __restrict__ Bt,
    short* __restrict__ Cb, float* __restrict__ Cf,
    const float* __restrict__ bias, const float* __restrict__ bsc,
    const float* __restrict__ resid,
    int M, int N, int K, long aBatch, long bBatch, long cBatch) {
  __shared__ __align__(16) short As[2][2][256 * 32];   // 64 KiB
  __shared__ __align__(16) short Bs[2][2][256 * 32];   // 64 KiB

  // bijective XCD-chunked remap
  const int gx = gridDim.x, gy = gridDim.y;
  const int nwg = gx * gy * gridDim.z;
  int lin = blockIdx.x + gx * (blockIdx.y + gy * blockIdx.z);
  int wg = lin;
  if ((nwg & 7) == 0) {
    const int cpx = nwg >> 3;
    wg = (lin & 7) * cpx + (lin >> 3);
  }
  const int NTN = N >> 8;
  const int ntile = wg % NTN;
  const int rest = wg / NTN;
  const int NTM = M >> 8;
  const int mtile = rest % NTM;
  const int bz = rest / NTM;

  const short* Ag = A + (long)bz * aBatch;
  const short* Bg = Bt + (long)bz * bBatch;
  const int m0 = mtile << 8, n0 = ntile << 8;
  const int tid = threadIdx.x;
  const int lane = tid & 63;
  const int wid = tid >> 6;
  const int wm = wid >> 2, wn = wid & 3;

  f32x4 acc[8][4];
#pragma unroll
  for (int i = 0; i < 8; ++i)
#pragma unroll
    for (int j = 0; j < 4; ++j) acc[i][j] = (f32x4){0.f, 0.f, 0.f, 0.f};

  const int NT = K >> 6;
  // half h: tile tau=h>>2, q=h&3: q0=A ks0, q1=B ks0, q2=A ks1, q3=B ks1
  auto stage = [&](int h) {
    const int tau = h >> 2, q = h & 3;
    const int buf = tau & 1, ks = q >> 1;
    short* ldsbase = (q & 1) ? &Bs[buf][ks][0] : &As[buf][ks][0];
    const short* gsrc = (q & 1) ? Bg : Ag;
    const int row0 = (q & 1) ? n0 : m0;
    const long k0 = (long)tau * 64 + ks * 32;
#pragma unroll
    for (int j = 0; j < 2; ++j) {
      const int o = tid * 16 + j * 8192;            // byte offset in 16KB half
      const int lo = SWZ(o);                        // inverse swizzle (involution)
      const int row = lo >> 6;
      const int cs = (lo & 63) >> 1;                // short col 0..31
      const short* gp;
      if (AMIR && !(q & 1)) {
        int grow = row0 + row;
        int b_ = grow >> 12, s_ = grow & (S - 1);
        int sm = (s_ <= 2048) ? s_ : (4096 - s_);
        gp = Ag + ((long)b_ * MH + sm) * K + k0 + cs;
      } else {
        gp = gsrc + (long)(row0 + row) * K + k0 + cs;
      }
      GLOAD(gp, (short*)((char*)ldsbase + o));
    }
  };

  // prologue: halves 0..6 (tile0 complete + tile1 A0,B0,A1), then vmcnt(6)
  for (int h = 0; h < 7; ++h) stage(h);
  asm volatile("s_waitcnt vmcnt(6)" ::: "memory");
  SBAR();

  short8 bf[4];
  for (int t = 0; t < NT; ++t) {
    const int buf = t & 1;
#pragma unroll
    for (int p = 0; p < 4; ++p) {
      const int ks = p >> 1, mh = p & 1;
      short8 af[4];
      {
        const short* Ah = &As[buf][ks][0];
        const int kb = (lane >> 4) * 16;                   // k byte offset
        const int r0 = wm * 128 + mh * 64 + (lane & 15);
#pragma unroll
        for (int i = 0; i < 4; ++i) {
          int byte = (r0 + i * 16) * 64 + kb;
          byte = SWZ(byte);
          af[i] = *(const short8*)((const char*)Ah + byte);
        }
        if (mh == 0) {
          const short* Bh = &Bs[buf][ks][0];
          const int c0 = wn * 64 + (lane & 15);
#pragma unroll
          for (int j = 0; j < 4; ++j) {
            int byte = (c0 + j * 16) * 64 + kb;
            byte = SWZ(byte);
            bf[j] = *(const short8*)((const char*)Bh + byte);
          }
        }
      }
      { const int h = 4 * t + p + 7; if (h < 4 * NT) stage(h); }
      SBAR();
      WAITL0();
      __builtin_amdgcn_s_setprio(1);
#pragma unroll
      for (int i = 0; i < 4; ++i)
#pragma unroll
        for (int j = 0; j < 4; ++j)
          acc[mh * 4 + i][j] = __builtin_amdgcn_mfma_f32_16x16x32_bf16(
              af[i], bf[j], acc[mh * 4 + i][j], 0, 0, 0);
      __builtin_amdgcn_s_setprio(0);
      if (p == 3) {
        if (t < NT - 2) {
          asm volatile("s_waitcnt vmcnt(6)" ::: "memory");
        } else if (t == NT - 2) {
          asm volatile("s_waitcnt vmcnt(0)" ::: "memory");
        }
      }
      SBAR();
    }
  }

  // epilogue: C/D layout col = lane&15, row = (lane>>4)*4 + reg
  const int rl = (lane >> 4) << 2;
#pragma unroll
  for (int f = 0; f < 8; ++f) {
    const int rbase = m0 + wm * 128 + f * 16 + rl;
#pragma unroll
    for (int j = 0; j < 4; ++j) {
      const int col = n0 + wn * 64 + j * 16 + (lane & 15);
      f32x4 a = acc[f][j];
      if constexpr (EPI == 0) {
        short* cp = Cb + (long)bz * cBatch;
#pragma unroll
        for (int r = 0; r < 4; ++r)
          cp[(long)(rbase + r) * N + col] = (short)f2bf(a[r]);
      } else if constexpr (EPI == 1) {
        float sc = bsc ? bsc[0] : 1.f;
        float bi = bias ? bias[col] * sc : 0.f;
        int b_ = rbase >> 12;
        int s_ = rbase & (S - 1);
        long addr = ((long)(b_ * DM + col)) * S + s_;
        u16x4 pk;
#pragma unroll
        for (int r = 0; r < 4; ++r) pk[r] = f2bf(a[r] + bi);
        *(u16x4*)(Cb + addr) = pk;
      } else {
        float bi = bias[col];
#pragma unroll
        for (int r = 0; r < 4; ++r) {
          long o = (long)(rbase + r) * N + col;
          Cf[o] = a[r] + bi + resid[o];
        }
      }
    }
  }
}

// ---------------- launch ----------------
extern "C" void kernel_launch(void* const* d_in, const int* in_sizes, int n_in,
                              void* d_out, int out_size, void* d_ws, size_t ws_size,
                              hipStream_t stream) {
  const float* x     = (const float*)d_in[0];
  const float* fd    = (const float*)d_in[1];
  const float* Wq    = (const float*)d_in[2];
  const float* bq    = (const float*)d_in[3];
  const float* Wk    = (const float*)d_in[4];
  const float* bk    = (const float*)d_in[5];
  const float* Wv    = (const float*)d_in[6];
  const float* bv    = (const float*)d_in[7];
  const float* Wo    = (const float*)d_in[8];
  const float* bo    = (const float*)d_in[9];
  const float* alpha = (const float*)d_in[10];
  const float* fsc   = (const float*)d_in[11];
  float* out = (float*)d_out;

  // --- workspace layout (~106.5 MB total) ---
  char* wp = (char*)d_ws;
  auto alloc = [&](size_t bytes) {
    char* p = wp;
    wp += (bytes + 255) & ~(size_t)255;
    return p;
  };
  float* cos_tab = (float*)alloc(S * 4);
  float* c_arr   = (float*)alloc(S * 4);          // c_arr[0] = c0 bias factor
  float* g       = (float*)alloc(S * 4);
  float* logits  = (float*)alloc((size_t)NB * NH * S * 4);   // 1 MB
  float* wsm     = (float*)alloc((size_t)NB * NH * S * 4);   // 1 MB
  short* WqT = (short*)alloc((size_t)DM * DM * 2);           // 2 MB each
  short* WkT = (short*)alloc((size_t)DM * DM * 2);
  short* WvT = (short*)alloc((size_t)DM * DM * 2);
  short* WoT = (short*)alloc((size_t)DM * DM * 2);
  short* slotA = (short*)alloc((size_t)NB * DS * 2);  // 32 MB: XbT -> Vt/att
  short* slotB = (short*)alloc((size_t)NB * DS * 2);  // 32 MB: G   -> Mc2 + A2t
  short* slotC = (short*)alloc((size_t)NB * DS * 2);  // 32 MB: Xs  -> att_time_half

  // d_out as scratch until the final GEMM (written fully before each read)
  short* QtT = (short*)d_out;
  short* KtT = (short*)d_out + (size_t)2 * DS;

  short* XbT = slotA;
  short* Gm  = slotB;
  short* Xs  = slotC;
  short* VtT = slotA;
  short* Mc2 = slotB;                                   // 9.73 MB
  short* A2t = (short*)((char*)slotB + 10u * 1024 * 1024);  // 17.3 MB
  short* att_half = slotC;                              // [b][MH][DM] 18.9 MB

  dim3 blk(256), blk8(512);

  // tables + transform matrix
  k_tables<<<dim3(S / 256), blk, 0, stream>>>(fd, alpha, fsc, cos_tab, c_arr);
  k_g<<<dim3(S / 256), blk, 0, stream>>>(cos_tab, c_arr, g);
  k_buildG<<<dim3((unsigned)((long)S * S / 8 / 256)), blk, 0, stream>>>(g, Gm);

  // casts / transposes (coalesced tiled)
  k_transW<<<dim3(16, 16), blk, 0, stream>>>(Wq, WqT);
  k_transW<<<dim3(16, 16), blk, 0, stream>>>(Wk, WkT);
  k_transW<<<dim3(16, 16), blk, 0, stream>>>(Wv, WvT);
  k_transW<<<dim3(16, 16), blk, 0, stream>>>(Wo, WoT);
  k_transX<<<dim3(S / 64, DM / 64, NB), blk, 0, stream>>>(x, XbT);

  // Xs_b = G @ X_b  (spectral applied ONCE, before projections)  [b][s][d] bf16
  dim3 gspec(DM / 256, S / 256, NB);     // 256 wg
  gemm8<0><<<gspec, blk8, 0, stream>>>(Gm, XbT, Xs, nullptr, nullptr, nullptr, nullptr,
                                       S, DM, S, 0, DS, DS);

  // q_t/k_t/v_t = Xs @ W + c0*b, written transposed [b][d][s]
  dim3 gproj(DM / 256, MTOT / 256, 1);   // 256 wg
  gemm8<1><<<gproj, blk8, 0, stream>>>(Xs, WqT, QtT, nullptr, bq, c_arr, nullptr,
                                       MTOT, DM, DM, 0, 0, 0);
  gemm8<1><<<gproj, blk8, 0, stream>>>(Xs, WkT, KtT, nullptr, bk, c_arr, nullptr,
                                       MTOT, DM, DM, 0, 0, 0);
  gemm8<1><<<gproj, blk8, 0, stream>>>(Xs, WvT, VtT, nullptr, bv, c_arr, nullptr,
                                       MTOT, DM, DM, 0, 0, 0);

  // logits, softmax over heads, attended (in-place on v_t)
  k_logits<<<dim3(S / 256, NH, NB), blk, 0, stream>>>(QtT, KtT, logits);
  k_softw<<<dim3(NB * S / 256), blk, 0, stream>>>(logits, wsm);
  k_att<<<dim3((unsigned)((long)NB * DS / 8 / 256)), blk, 0, stream>>>(VtT, wsm);

  // fold att columns (even symmetry of ifft cos basis), build half-cos matrix,
  // then att_time_half = Mc2 @ A2  (rows n=0..2048 of ifft; rest mirrored)
  k_fold<<<dim3(KH / 256 + 1, DM, NB), blk, 0, stream>>>(VtT, A2t);
  k_buildM2<<<dim3((unsigned)((long)MH * KH / 8 / 256)), blk, 0, stream>>>(cos_tab, Mc2);
  dim3 ghalf(DM / 256, MH / 256, NB);    // (4,9,4) = 144 wg
  gemm8<0><<<ghalf, blk8, 0, stream>>>(Mc2, A2t, att_half, nullptr, nullptr, nullptr, nullptr,
                                       MH, DM, KH, 0, (long)DM * KH, (long)MH * DM);

  // out = att_time @ Wo + bo + x  (A rows read via mirror map; fp32 epilogue)
  gemm8<2, 1><<<gproj, blk8, 0, stream>>>(att_half, WoT, nullptr, out, bo, nullptr, x,
                                          MTOT, DM, DM, 0, 0, 0);
}